// Round 11
// baseline (643.126 us; speedup 1.0000x reference)
//
#include <hip/hip_runtime.h>
#include <hip/hip_bf16.h>

#define H 128

typedef __attribute__((ext_vector_type(8))) _Float16 f16x8;
typedef __attribute__((ext_vector_type(4))) float f32x4;

static inline size_t align_up(size_t x, size_t a){ return (x + a - 1) & ~(a - 1); }

__device__ inline f32x4 mfma16h(f16x8 a, f16x8 b, f32x4 c){
  return __builtin_amdgcn_mfma_f32_16x16x32_f16(a, b, c, 0, 0, 0);
}

// async global->LDS, 16B per lane. LDS dest linear; swizzle via pre-swizzled global source.
__device__ inline void gload_lds16(const void* g, void* l){
  __builtin_amdgcn_global_load_lds(
      (const __attribute__((address_space(1))) void*)g,
      (__attribute__((address_space(3))) void*)l, 16, 0, 0);
}

// ---------------- weight pre-pack args ----------------
struct PackArgs {
  const float* src[10];
  _Float16* dst[10];
  int K[10];
  int start[11];
};

// ---------------- merged pack_w + hist_buckets ----------------
__global__ __launch_bounds__(256) void pack_hist(PackArgs pa, int nblk_pack,
    const int* __restrict__ src, const int* __restrict__ dst, int E,
    int* __restrict__ cnt_b_p, int* __restrict__ cnt_b_t, int histgrid){
  if ((int)blockIdx.x < nblk_pack){
    int t = blockIdx.x * 256 + threadIdx.x;
    if (t >= pa.start[10]) return;
    int m = 0;
    #pragma unroll
    for (int i = 1; i < 10; i++) if (t >= pa.start[i]) m = i;
    int local = t - pa.start[m];
    int k = local >> 7, n = local & 127;
    float w = pa.src[m][local];
    _Float16 hi = (_Float16)w;
    _Float16 lo = (_Float16)(w - (float)hi);
    _Float16* d = pa.dst[m];
    int Km = pa.K[m];
    d[n * Km + k] = hi;
    d[128 * Km + n * Km + k] = lo;
  } else {
    int bid = (int)blockIdx.x - nblk_pack;
    __shared__ int hp[256], ht[256];
    int tid = threadIdx.x;
    hp[tid] = 0; ht[tid] = 0;
    __syncthreads();
    for (int i = bid * 256 + tid; i < E; i += histgrid * 256){
      atomicAdd(&hp[dst[i] >> 7], 1);
      atomicAdd(&ht[src[i] >> 9], 1);
    }
    __syncthreads();
    if (hp[tid]) atomicAdd(&cnt_b_p[tid], hp[tid]);
    if (ht[tid]) atomicAdd(&cnt_b_t[tid], ht[tid]);
  }
}

// ---------------- tiny scan of bucket counts -> bases + cursors ----------------
__global__ void scan_buckets(const int* __restrict__ cb_p, const int* __restrict__ cb_t, int nbp, int nbt,
                             int* __restrict__ base_p, int* __restrict__ base_t,
                             int* __restrict__ cur_p, int* __restrict__ cur_t){
  if (threadIdx.x == 0){
    int s = 0;
    for (int i = 0; i < nbp; i++){ base_p[i] = s; cur_p[i] = s; s += cb_p[i]; }
    base_p[nbp] = s;
  } else if (threadIdx.x == 1){
    int s = 0;
    for (int i = 0; i < nbt; i++){ base_t[i] = s; cur_t[i] = s; s += cb_t[i]; }
    base_t[nbt] = s;
  }
}

// ---------------- bin edges body (per-block LDS counting sort) ----------------
__device__ inline void bin_body(const int* __restrict__ keys, const int* __restrict__ vals,
    int E, int shift, int nb, int* __restrict__ cursor, unsigned* __restrict__ rec_out, int chunk,
    int* hist, int* excl, int* gbase, unsigned* recs, unsigned char* binid){
  const int CH = 4096, IT = 16;
  int tid = threadIdx.x;
  int start = chunk * CH;
  int cnt = E - start; if (cnt > CH) cnt = CH;
  if (cnt <= 0) return;
  hist[tid] = 0;
  __syncthreads();
  int b[IT]; int rank[IT]; unsigned rc[IT];
  unsigned mask = (1u << shift) - 1u;
  #pragma unroll
  for (int q = 0; q < IT; q++){
    int i = tid + q * 256;
    if (i < cnt){
      int k = keys[start + i], v = vals[start + i];
      b[q] = k >> shift;
      rc[q] = ((unsigned)v << shift) | ((unsigned)k & mask);
      rank[q] = atomicAdd(&hist[b[q]], 1);
    } else b[q] = -1;
  }
  __syncthreads();
  int lane = tid & 63, wid = tid >> 6;
  if (wid == 0){
    int h0 = hist[lane*4], h1 = hist[lane*4+1], h2 = hist[lane*4+2], h3 = hist[lane*4+3];
    int s = h0 + h1 + h2 + h3;
    int sc = s;
    #pragma unroll
    for (int o = 1; o < 64; o <<= 1){ int t = __shfl_up(sc, (unsigned)o, 64); if (lane >= o) sc += t; }
    int base = sc - s;
    excl[lane*4] = base; excl[lane*4+1] = base + h0;
    excl[lane*4+2] = base + h0 + h1; excl[lane*4+3] = base + h0 + h1 + h2;
  }
  __syncthreads();
  #pragma unroll
  for (int q = 0; q < IT; q++){
    if (b[q] >= 0){
      int pos = excl[b[q]] + rank[q];
      recs[pos] = rc[q];
      binid[pos] = (unsigned char)b[q];
    }
  }
  if (tid < nb && hist[tid] > 0) gbase[tid] = atomicAdd(&cursor[tid], hist[tid]);
  __syncthreads();
  for (int i = tid; i < cnt; i += 256){
    int bb = binid[i];
    rec_out[gbase[bb] + (i - excl[bb])] = recs[i];
  }
}

// merged bin_edges: P chunks then T chunks
__global__ __launch_bounds__(256) void bin2(const int* __restrict__ esrc, const int* __restrict__ edst,
    int E, int nb_p, int* cu_p, unsigned* rec_p, int nb_t, int* cu_t, unsigned* rec_t, int nchunks){
  __shared__ int hist[256];
  __shared__ int excl[256];
  __shared__ int gbase[256];
  __shared__ unsigned recs[4096];
  __shared__ unsigned char binid[4096];
  if ((int)blockIdx.x < nchunks)
    bin_body(edst, esrc, E, 7, nb_p, cu_p, rec_p, blockIdx.x, hist, excl, gbase, recs, binid);
  else
    bin_body(esrc, edst, E, 9, nb_t, cu_t, rec_t, blockIdx.x - nchunks, hist, excl, gbase, recs, binid);
}

// ---------------- per-bucket CSR build body ----------------
template<int LOC, int LB>
__device__ inline void build_body(const unsigned* __restrict__ rec, const int* __restrict__ bbase,
    int nkeys, int E, int* __restrict__ off, float* __restrict__ inv, int* __restrict__ csr,
    int b, int nb, int* hist, int* excl, int* cur, int* wsum){
  int tid = threadIdx.x;
  int s = bbase[b], e = bbase[b + 1];
  for (int k = tid; k < LOC; k += 256){ hist[k] = 0; cur[k] = 0; }
  __syncthreads();
  for (int i = s + tid; i < e; i += 256) atomicAdd(&hist[rec[i] & (LOC - 1)], 1);
  __syncthreads();
  int lane = tid & 63, wid = tid >> 6;
  constexpr int BPT = (LOC + 255) / 256;
  int h[BPT]; int ssum = 0;
  #pragma unroll
  for (int q = 0; q < BPT; q++){
    int k = tid * BPT + q;
    h[q] = (k < LOC) ? hist[k] : 0;
    ssum += h[q];
  }
  int sc = ssum;
  #pragma unroll
  for (int o = 1; o < 64; o <<= 1){ int t = __shfl_up(sc, (unsigned)o, 64); if (lane >= o) sc += t; }
  if (lane == 63) wsum[wid] = sc;
  __syncthreads();
  int base = 0;
  for (int w = 0; w < wid; w++) base += wsum[w];
  int ex = base + sc - ssum;
  #pragma unroll
  for (int q = 0; q < BPT; q++){
    int k = tid * BPT + q;
    if (k < LOC) excl[k] = ex;
    ex += h[q];
  }
  __syncthreads();
  int keybase = b << LB;
  for (int k = tid; k < LOC; k += 256){
    int gk = keybase + k;
    if (gk < nkeys){
      off[gk] = s + excl[k];
      int c = hist[k];
      inv[gk] = 1.0f / (float)(c > 1 ? c : 1);
    }
  }
  if (b == nb - 1 && tid == 0) off[nkeys] = E;
  for (int i = s + tid; i < e; i += 256){
    unsigned r = rec[i];
    int k = (int)(r & (LOC - 1));
    int rk = atomicAdd(&cur[k], 1);
    csr[s + excl[k] + rk] = (int)(r >> LB);
  }
}

// merged build_csr: P buckets (LOC=128) then T buckets (LOC=512)
__global__ __launch_bounds__(256) void build2(
    const unsigned* rec_p, const int* bb_p, int NPk, int* off_p, float* inv_p, int* csr_p, int nb_p,
    const unsigned* rec_t, const int* bb_t, int NTk, int* off_t, float* inv_t, int* csr_t, int nb_t, int E){
  __shared__ int hist[512];
  __shared__ int excl[512];
  __shared__ int cur[512];
  __shared__ int wsum[8];
  if ((int)blockIdx.x < nb_p)
    build_body<128,7>(rec_p, bb_p, NPk, E, off_p, inv_p, csr_p, blockIdx.x, nb_p, hist, excl, cur, wsum);
  else
    build_body<512,9>(rec_t, bb_t, NTk, E, off_t, inv_t, csr_t, blockIdx.x - nb_p, nb_t, hist, excl, cur, wsum);
}

// ---------------- merged input projections (fp32 A -> f16 OUT), pipelined ----------------
struct ProjJob {
  const float* A;
  const _Float16* WT;
  const float* bias;
  _Float16* OUT;
  int M;
  int ntiles;
  int nblk;
};
template<int KA>
__device__ inline void proj_body(ProjJob j, int bid, char* lds){
  constexpr int KST = KA / 32;
  constexpr int RB_A = KA * 4;
  constexpr int CHA = RB_A / 16;
  constexpr int NIA = 64 * CHA / 512;
  constexpr int ABYTES = 64 * RB_A;

  const int t    = threadIdx.x;
  const int wid  = t >> 6;
  const int lane = t & 63;
  const int l15  = lane & 15;
  const int lkg  = lane >> 4;
  const int colg = wid * 16 + l15;
  const int M = j.M, ntiles = j.ntiles, nblk = j.nblk;

  f16x8 wl_hi[KST], wl_lo[KST];
  {
    const _Float16* bh = j.WT + (size_t)colg * KA + lkg * 8;
    #pragma unroll
    for (int ks = 0; ks < KST; ks++){
      wl_hi[ks] = *(const f16x8*)(bh + ks * 32);
      wl_lo[ks] = *(const f16x8*)(bh + 128 * KA + ks * 32);
    }
  }
  const float bb = j.bias[colg];

  auto stage = [&](int tile, char* dstA){
    int row0 = tile * 64;
    #pragma unroll
    for (int q = 0; q < NIA; q++){
      int lc  = q * 512 + t;
      int row = lc / CHA;
      int ch  = lc - row * CHA;
      int grow = row0 + row; if (grow > M - 1) grow = M - 1;
      int gch = ch ^ (row & 7);
      gload_lds16((const char*)j.A + (size_t)grow * RB_A + gch * 16, dstA + lc * 16);
    }
  };

  int p = 0;
  if (bid < ntiles) stage(bid, lds);

  for (int t0 = bid; t0 < ntiles; t0 += nblk){
    const int row0 = t0 * 64;
    const int tn = t0 + nblk;
    const bool hasnext = tn < ntiles;
    if (hasnext) stage(tn, lds + (p ^ 1) * ABYTES);

    if (hasnext){
      if constexpr (NIA == 4) asm volatile("s_waitcnt vmcnt(4)" ::: "memory");
      else                    asm volatile("s_waitcnt vmcnt(2)" ::: "memory");
    } else {
      asm volatile("s_waitcnt vmcnt(0)" ::: "memory");
    }
    __builtin_amdgcn_s_barrier();
    asm volatile("" ::: "memory");

    const char* bufA = lds + p * ABYTES;

    f32x4 acc[4];
    #pragma unroll
    for (int tt = 0; tt < 4; tt++){
      acc[tt] = (f32x4){0.f, 0.f, 0.f, 0.f};
      const int rl = tt * 16 + l15;
      const int sw = rl & 7;
      const char* ap = bufA + rl * RB_A;
      #pragma unroll
      for (int ks = 0; ks < KST; ks++){
        int c0 = lkg * 2 + ks * 8;
        f32x4 a0 = *(const f32x4*)(ap + ((c0    ) ^ sw) * 16);
        f32x4 a1 = *(const f32x4*)(ap + ((c0 + 1) ^ sw) * 16);
        f16x8 af;
        #pragma unroll
        for (int e = 0; e < 8; e++) af[e] = (_Float16)(e < 4 ? a0[e] : a1[e - 4]);
        acc[tt] = mfma16h(af, wl_hi[ks], acc[tt]);
        acc[tt] = mfma16h(af, wl_lo[ks], acc[tt]);
      }
      acc[tt].x += bb; acc[tt].y += bb; acc[tt].z += bb; acc[tt].w += bb;
    }

    #pragma unroll
    for (int tt = 0; tt < 4; tt++){
      #pragma unroll
      for (int r = 0; r < 4; r++){
        int row = row0 + tt * 16 + lkg * 4 + r;
        if (row < M) j.OUT[(size_t)row * H + colg] = (_Float16)acc[tt][r];
      }
    }
    asm volatile("s_waitcnt lgkmcnt(0)" ::: "memory");
    __builtin_amdgcn_s_barrier();
    asm volatile("" ::: "memory");
    p ^= 1;
  }
}
__global__ __launch_bounds__(512) void proj2(ProjJob jt, ProjJob jp){
  __shared__ __align__(16) char lds[2 * 64 * 512];
  if ((int)blockIdx.x < jt.nblk) proj_body<128>(jt, blockIdx.x, lds);
  else                           proj_body<64>(jp, (int)blockIdx.x - jt.nblk, lds);
}

// ---------------- fused agg + SAGE GEMM: block = one 64-row dst tile, two jobs per launch ----------------
// Phase G: gather-mean neighbor rows (f32 accum, agg2 summation order) -> f16 -> swizzled LDS A-tile;
//          self rows staged to LDS B via global_load_lds (issued first, hidden under gather).
// Phase M: dual MFMA (A@Wl + B@Wr) + bias + l2norm [+relu], f16 store. (sage_mfma2 body)
struct FusedJob {
  const _Float16* feat;   // gather table (other side's features)
  const int* csr;
  const int* off;
  const float* inv;
  const _Float16* Bs;     // self features
  const _Float16* WlT;
  const _Float16* WrT;
  const float* bias;
  _Float16* OUT;
  int M;
  int ntiles;
};
template<bool RELU>
__global__ __launch_bounds__(512) void fused_sage(FusedJob j0, FusedJob j1){
  __shared__ __align__(16) char ldsA[64 * 256];
  __shared__ __align__(16) char ldsB[64 * 256];
  __shared__ float red[8][64];

  const bool second = (int)blockIdx.x >= j0.ntiles;
  const FusedJob j = second ? j1 : j0;
  const int tile = (int)blockIdx.x - (second ? j0.ntiles : 0);
  const int M = j.M;
  const int row0 = tile * 64;

  const int t    = threadIdx.x;
  const int wid  = t >> 6;
  const int lane = t & 63;
  const int l15  = lane & 15;
  const int lkg  = lane >> 4;
  const int colg = wid * 16 + l15;

  // stage self rows (B) async — completes under the gather
  #pragma unroll
  for (int q = 0; q < 2; q++){
    int lc = q * 512 + t;
    int row = lc >> 4, ch = lc & 15;
    int grow = row0 + row; if (grow > M - 1) grow = M - 1;
    int gch = ch ^ (row & 7);
    gload_lds16((const char*)j.Bs + (size_t)grow * 256 + gch * 16, ldsB + lc * 16);
  }

  // ---- Phase G: gather+mean, 32 groups x 16 lanes, 2 rows/group ----
  {
    const int g = t >> 4, l = t & 15;
    const _Float16* F = j.feat;
    #pragma unroll
    for (int rr = 0; rr < 2; rr++){
      int r  = g * 2 + rr;
      int gr = row0 + r;
      int grc = gr < M ? gr : M - 1;
      int s = j.off[grc], e = j.off[grc + 1];
      float c0[8], c1[8], c2[8], c3[8];
      #pragma unroll
      for (int q = 0; q < 8; q++){ c0[q] = 0.f; c1[q] = 0.f; c2[q] = 0.f; c3[q] = 0.f; }
      int i = s;
      for (; i + 3 < e; i += 4){
        f16x8 v0 = *(const f16x8*)(F + (size_t)j.csr[i]     * H + l * 8);
        f16x8 v1 = *(const f16x8*)(F + (size_t)j.csr[i + 1] * H + l * 8);
        f16x8 v2 = *(const f16x8*)(F + (size_t)j.csr[i + 2] * H + l * 8);
        f16x8 v3 = *(const f16x8*)(F + (size_t)j.csr[i + 3] * H + l * 8);
        #pragma unroll
        for (int q = 0; q < 8; q++){
          c0[q] += (float)v0[q]; c1[q] += (float)v1[q];
          c2[q] += (float)v2[q]; c3[q] += (float)v3[q];
        }
      }
      for (; i < e; i++){
        f16x8 v0 = *(const f16x8*)(F + (size_t)j.csr[i] * H + l * 8);
        #pragma unroll
        for (int q = 0; q < 8; q++) c0[q] += (float)v0[q];
      }
      float iv = j.inv[grc];
      f16x8 ov;
      #pragma unroll
      for (int q = 0; q < 8; q++){
        float rv = (c0[q] + c1[q]) + (c2[q] + c3[q]);
        ov[q] = (_Float16)(rv * iv);
      }
      *(f16x8*)(ldsA + r * 256 + ((l ^ (r & 7)) * 16)) = ov;
    }
  }

  // ---- W fragments (after gather: keeps gather-phase VGPRs low) ----
  f16x8 wl_hi[4], wl_lo[4], wr_hi[4], wr_lo[4];
  {
    const _Float16* bh  = j.WlT + (size_t)colg * 128 + lkg * 8;
    const _Float16* bh2 = j.WrT + (size_t)colg * 128 + lkg * 8;
    #pragma unroll
    for (int ks = 0; ks < 4; ks++){
      wl_hi[ks] = *(const f16x8*)(bh + ks * 32);
      wl_lo[ks] = *(const f16x8*)(bh + 128 * 128 + ks * 32);
      wr_hi[ks] = *(const f16x8*)(bh2 + ks * 32);
      wr_lo[ks] = *(const f16x8*)(bh2 + 128 * 128 + ks * 32);
    }
  }
  const float bb = j.bias[colg];

  asm volatile("s_waitcnt vmcnt(0) lgkmcnt(0)" ::: "memory");
  __builtin_amdgcn_s_barrier();
  asm volatile("" ::: "memory");

  // ---- Phase M: dual GEMM + norm (+relu) + store ----
  f32x4 acc[4];
  #pragma unroll
  for (int tt = 0; tt < 4; tt++){
    acc[tt] = (f32x4){0.f, 0.f, 0.f, 0.f};
    const int rl = tt * 16 + l15;
    const int sw = rl & 7;
    const char* ap = ldsA + rl * 256;
    #pragma unroll
    for (int ks = 0; ks < 4; ks++){
      f16x8 af = *(const f16x8*)(ap + ((ks * 4 + lkg) ^ sw) * 16);
      acc[tt] = mfma16h(af, wl_hi[ks], acc[tt]);
      acc[tt] = mfma16h(af, wl_lo[ks], acc[tt]);
    }
    const char* bp = ldsB + rl * 256;
    #pragma unroll
    for (int ks = 0; ks < 4; ks++){
      f16x8 bf = *(const f16x8*)(bp + ((ks * 4 + lkg) ^ sw) * 16);
      acc[tt] = mfma16h(bf, wr_hi[ks], acc[tt]);
      acc[tt] = mfma16h(bf, wr_lo[ks], acc[tt]);
    }
    acc[tt].x += bb; acc[tt].y += bb; acc[tt].z += bb; acc[tt].w += bb;
  }

  #pragma unroll
  for (int tt = 0; tt < 4; tt++){
    #pragma unroll
    for (int r = 0; r < 4; r++){
      float v = acc[tt][r] * acc[tt][r];
      v += __shfl_xor(v, 1, 64);
      v += __shfl_xor(v, 2, 64);
      v += __shfl_xor(v, 4, 64);
      v += __shfl_xor(v, 8, 64);
      if (l15 == 0) red[wid][tt * 16 + lkg * 4 + r] = v;
    }
  }
  asm volatile("s_waitcnt lgkmcnt(0)" ::: "memory");
  __builtin_amdgcn_s_barrier();
  asm volatile("" ::: "memory");
  #pragma unroll
  for (int tt = 0; tt < 4; tt++){
    #pragma unroll
    for (int r = 0; r < 4; r++){
      int idx = tt * 16 + lkg * 4 + r;
      float s = 0.f;
      #pragma unroll
      for (int w2 = 0; w2 < 8; w2++) s += red[w2][idx];
      float scale = 1.f / fmaxf(sqrtf(s), 1e-12f);
      float v = acc[tt][r] * scale;
      if (RELU) v = fmaxf(v, 0.f);
      acc[tt][r] = v;
    }
  }
  #pragma unroll
  for (int tt = 0; tt < 4; tt++){
    #pragma unroll
    for (int r = 0; r < 4; r++){
      int row = row0 + tt * 16 + lkg * 4 + r;
      if (row < M) j.OUT[(size_t)row * H + colg] = (_Float16)acc[tt][r];
    }
  }
}

// ---------------- link predictor: 16-lane group per pair, 16B loads ----------------
__global__ __launch_bounds__(256) void dot_kernel(const _Float16* __restrict__ zt, const _Float16* __restrict__ zp,
                           const int* __restrict__ ls, const int* __restrict__ ld,
                           float* __restrict__ out, int n){
  int w = (blockIdx.x * 256 + threadIdx.x) >> 4;
  int l = threadIdx.x & 15;
  if (w >= n) return;
  f16x8 x = *(const f16x8*)&zt[(size_t)ls[w] * H + l * 8];
  f16x8 y = *(const f16x8*)&zp[(size_t)ld[w] * H + l * 8];
  float v = 0.f;
  #pragma unroll
  for (int q = 0; q < 8; q++) v += (float)x[q] * (float)y[q];
  v += __shfl_xor(v, 1, 64);
  v += __shfl_xor(v, 2, 64);
  v += __shfl_xor(v, 4, 64);
  v += __shfl_xor(v, 8, 64);
  if (l == 0) out[w] = v;
}

extern "C" void kernel_launch(void* const* d_in, const int* in_sizes, int n_in,
                              void* d_out, int out_size, void* d_ws, size_t ws_size,
                              hipStream_t stream){
  const float* x_t  = (const float*)d_in[0];
  const float* x_p  = (const float*)d_in[1];
  const int*   esrc = (const int*)d_in[2];
  const int*   edst = (const int*)d_in[3];
  const int*   lsrc = (const int*)d_in[4];
  const int*   ldst = (const int*)d_in[5];
  const float* Wn_t = (const float*)d_in[6];
  const float* bn_t = (const float*)d_in[7];
  const float* Wn_p = (const float*)d_in[8];
  const float* bn_p = (const float*)d_in[9];
  const float* W1_l_p=(const float*)d_in[10]; const float* b1_p=(const float*)d_in[11]; const float* W1_r_p=(const float*)d_in[12];
  const float* W1_l_t=(const float*)d_in[13]; const float* b1_t=(const float*)d_in[14]; const float* W1_r_t=(const float*)d_in[15];
  const float* W2_l_p=(const float*)d_in[16]; const float* b2_p=(const float*)d_in[17]; const float* W2_r_p=(const float*)d_in[18];
  const float* W2_l_t=(const float*)d_in[19]; const float* b2_t=(const float*)d_in[20]; const float* W2_r_t=(const float*)d_in[21];
  float* out = (float*)d_out;

  const int FT = 128, FP = 64;
  int NT = in_sizes[0] / FT;
  int NP = in_sizes[1] / FP;
  int E  = in_sizes[2];
  int EL = in_sizes[4];

  const int SH_P = 7, SH_T = 9;
  int nb_p = (NP + (1 << SH_P) - 1) >> SH_P;
  int nb_t = (NT + (1 << SH_T) - 1) >> SH_T;

  char* base = (char*)d_ws;
  size_t o = 0;
  auto alloc = [&](size_t bytes) -> char* { char* p = base + o; o = align_up(o + bytes, 256); return p; };
  int*   cb_p  = (int*)alloc(256 * 4);
  int*   cb_t  = (int*)alloc(256 * 4);
  size_t zero_bytes = o;
  int*   bb_p  = (int*)alloc(260 * 4);
  int*   bb_t  = (int*)alloc(260 * 4);
  int*   cu_p  = (int*)alloc(256 * 4);
  int*   cu_t  = (int*)alloc(256 * 4);
  int*   off_p = (int*)alloc((size_t)(NP + 1) * 4);
  int*   off_t = (int*)alloc((size_t)(NT + 1) * 4);
  float* inv_p = (float*)alloc((size_t)NP * 4);
  float* inv_t = (float*)alloc((size_t)NT * 4);
  unsigned* rec_p = (unsigned*)alloc((size_t)E * 4);
  unsigned* rec_t = (unsigned*)alloc((size_t)E * 4);
  int*   csr_p = (int*)alloc((size_t)E * 4);
  int*   csr_t = (int*)alloc((size_t)E * 4);
  _Float16* h_t = (_Float16*)alloc((size_t)NT * H * 2);
  _Float16* h_p = (_Float16*)alloc((size_t)NP * H * 2);
  _Float16* a_t = (_Float16*)alloc((size_t)NT * H * 2);
  _Float16* a_p = (_Float16*)alloc((size_t)NP * H * 2);

  PackArgs pa;
  const float* wsrc[10] = {Wn_t, Wn_p, W1_l_p, W1_r_p, W1_l_t, W1_r_t, W2_l_p, W2_r_p, W2_l_t, W2_r_t};
  int Ks[10] = {128, 64, 128, 128, 128, 128, 128, 128, 128, 128};
  _Float16* wpk[10];
  int st = 0;
  for (int m = 0; m < 10; m++){
    wpk[m] = (_Float16*)alloc((size_t)2 * 128 * Ks[m] * 2);
    pa.src[m] = wsrc[m]; pa.dst[m] = wpk[m]; pa.K[m] = Ks[m]; pa.start[m] = st;
    st += Ks[m] * 128;
  }
  pa.start[10] = st;
  (void)ws_size; (void)n_in; (void)out_size;

  hipMemsetAsync(base, 0, zero_bytes, stream);

  // merged pack_w + bucket histograms
  int nblk_pack = (st + 255) / 256;
  const int histgrid = 512;
  pack_hist<<<nblk_pack + histgrid, 256, 0, stream>>>(pa, nblk_pack, esrc, edst, E, cb_p, cb_t, histgrid);
  scan_buckets<<<1, 64, 0, stream>>>(cb_p, cb_t, nb_p, nb_t, bb_p, bb_t, cu_p, cu_t);
  int nchunks = (E + 4095) / 4096;
  bin2<<<2 * nchunks, 256, 0, stream>>>(esrc, edst, E, nb_p, cu_p, rec_p, nb_t, cu_t, rec_t, nchunks);
  build2<<<nb_p + nb_t, 256, 0, stream>>>(rec_p, bb_p, NP, off_p, inv_p, csr_p, nb_p,
                                          rec_t, bb_t, NT, off_t, inv_t, csr_t, nb_t, E);

  // merged input projections
  int tiles_t = (NT + 63) / 64;
  int tiles_p = (NP + 63) / 64;
  int pblk_t = tiles_t < 448 ? tiles_t : 448;
  int pblk_p = tiles_p < 64 ? tiles_p : 64;
  ProjJob pjt{x_t, wpk[0], bn_t, h_t, NT, tiles_t, pblk_t};
  ProjJob pjp{x_p, wpk[1], bn_p, h_p, NP, tiles_p, pblk_p};
  proj2<<<pblk_t + pblk_p, 512, 0, stream>>>(pjt, pjp);

  // fused agg+sage, layer 1: P gathers h_t, self h_p; T gathers h_p, self h_t
  FusedJob f1p{h_t, csr_p, off_p, inv_p, h_p, wpk[2], wpk[3], b1_p, a_p, NP, tiles_p};
  FusedJob f1t{h_p, csr_t, off_t, inv_t, h_t, wpk[4], wpk[5], b1_t, a_t, NT, tiles_t};
  fused_sage<true><<<tiles_p + tiles_t, 512, 0, stream>>>(f1p, f1t);

  // fused agg+sage, layer 2: P gathers o_t(=a_t), self o_p(=a_p); T gathers o_p, self o_t
  FusedJob f2p{a_t, csr_p, off_p, inv_p, a_p, wpk[6], wpk[7], b2_p, h_p, NP, tiles_p};
  FusedJob f2t{a_p, csr_t, off_t, inv_t, a_t, wpk[8], wpk[9], b2_t, h_t, NT, tiles_t};
  fused_sage<false><<<tiles_p + tiles_t, 512, 0, stream>>>(f2p, f2t);

  // link prediction
  dot_kernel<<<(EL + 15) / 16, 256, 0, stream>>>(h_t, h_p, lsrc, ldst, out, EL);
}

// Round 12
// 494.245 us; speedup vs baseline: 1.3012x; 1.3012x over previous
//
#include <hip/hip_runtime.h>
#include <hip/hip_bf16.h>

#define H 128

typedef __attribute__((ext_vector_type(8))) _Float16 f16x8;
typedef __attribute__((ext_vector_type(4))) float f32x4;

static inline size_t align_up(size_t x, size_t a){ return (x + a - 1) & ~(a - 1); }

__device__ inline f32x4 mfma16h(f16x8 a, f16x8 b, f32x4 c){
  return __builtin_amdgcn_mfma_f32_16x16x32_f16(a, b, c, 0, 0, 0);
}

// async global->LDS, 16B per lane. LDS dest linear; swizzle via pre-swizzled global source.
__device__ inline void gload_lds16(const void* g, void* l){
  __builtin_amdgcn_global_load_lds(
      (const __attribute__((address_space(1))) void*)g,
      (__attribute__((address_space(3))) void*)l, 16, 0, 0);
}

// ---------------- weight pre-pack args: W[K][128] fp32 -> WT[128][K] f16 (single) ----------------
struct PackArgs {
  const float* src[10];
  _Float16* dst[10];
  int K[10];
  int start[11];
};

// ---------------- merged pack_w + hist_buckets ----------------
__global__ __launch_bounds__(256) void pack_hist(PackArgs pa, int nblk_pack,
    const int* __restrict__ src, const int* __restrict__ dst, int E,
    int* __restrict__ cnt_b_p, int* __restrict__ cnt_b_t, int histgrid){
  if ((int)blockIdx.x < nblk_pack){
    int t = blockIdx.x * 256 + threadIdx.x;
    if (t >= pa.start[10]) return;
    int m = 0;
    #pragma unroll
    for (int i = 1; i < 10; i++) if (t >= pa.start[i]) m = i;
    int local = t - pa.start[m];
    int k = local >> 7, n = local & 127;
    float w = pa.src[m][local];
    pa.dst[m][n * pa.K[m] + k] = (_Float16)w;
  } else {
    int bid = (int)blockIdx.x - nblk_pack;
    __shared__ int hp[256], ht[256];
    int tid = threadIdx.x;
    hp[tid] = 0; ht[tid] = 0;
    __syncthreads();
    for (int i = bid * 256 + tid; i < E; i += histgrid * 256){
      atomicAdd(&hp[dst[i] >> 7], 1);
      atomicAdd(&ht[src[i] >> 9], 1);
    }
    __syncthreads();
    if (hp[tid]) atomicAdd(&cnt_b_p[tid], hp[tid]);
    if (ht[tid]) atomicAdd(&cnt_b_t[tid], ht[tid]);
  }
}

// ---------------- tiny scan of bucket counts -> bases + cursors ----------------
__global__ void scan_buckets(const int* __restrict__ cb_p, const int* __restrict__ cb_t, int nbp, int nbt,
                             int* __restrict__ base_p, int* __restrict__ base_t,
                             int* __restrict__ cur_p, int* __restrict__ cur_t){
  if (threadIdx.x == 0){
    int s = 0;
    for (int i = 0; i < nbp; i++){ base_p[i] = s; cur_p[i] = s; s += cb_p[i]; }
    base_p[nbp] = s;
  } else if (threadIdx.x == 1){
    int s = 0;
    for (int i = 0; i < nbt; i++){ base_t[i] = s; cur_t[i] = s; s += cb_t[i]; }
    base_t[nbt] = s;
  }
}

// ---------------- bin edges body (per-block LDS counting sort) ----------------
__device__ inline void bin_body(const int* __restrict__ keys, const int* __restrict__ vals,
    int E, int shift, int nb, int* __restrict__ cursor, unsigned* __restrict__ rec_out, int chunk,
    int* hist, int* excl, int* gbase, unsigned* recs, unsigned char* binid){
  const int CH = 4096, IT = 16;
  int tid = threadIdx.x;
  int start = chunk * CH;
  int cnt = E - start; if (cnt > CH) cnt = CH;
  if (cnt <= 0) return;
  hist[tid] = 0;
  __syncthreads();
  int b[IT]; int rank[IT]; unsigned rc[IT];
  unsigned mask = (1u << shift) - 1u;
  #pragma unroll
  for (int q = 0; q < IT; q++){
    int i = tid + q * 256;
    if (i < cnt){
      int k = keys[start + i], v = vals[start + i];
      b[q] = k >> shift;
      rc[q] = ((unsigned)v << shift) | ((unsigned)k & mask);
      rank[q] = atomicAdd(&hist[b[q]], 1);
    } else b[q] = -1;
  }
  __syncthreads();
  int lane = tid & 63, wid = tid >> 6;
  if (wid == 0){
    int h0 = hist[lane*4], h1 = hist[lane*4+1], h2 = hist[lane*4+2], h3 = hist[lane*4+3];
    int s = h0 + h1 + h2 + h3;
    int sc = s;
    #pragma unroll
    for (int o = 1; o < 64; o <<= 1){ int t = __shfl_up(sc, (unsigned)o, 64); if (lane >= o) sc += t; }
    int base = sc - s;
    excl[lane*4] = base; excl[lane*4+1] = base + h0;
    excl[lane*4+2] = base + h0 + h1; excl[lane*4+3] = base + h0 + h1 + h2;
  }
  __syncthreads();
  #pragma unroll
  for (int q = 0; q < IT; q++){
    if (b[q] >= 0){
      int pos = excl[b[q]] + rank[q];
      recs[pos] = rc[q];
      binid[pos] = (unsigned char)b[q];
    }
  }
  if (tid < nb && hist[tid] > 0) gbase[tid] = atomicAdd(&cursor[tid], hist[tid]);
  __syncthreads();
  for (int i = tid; i < cnt; i += 256){
    int bb = binid[i];
    rec_out[gbase[bb] + (i - excl[bb])] = recs[i];
  }
}

// merged bin_edges: P chunks then T chunks
__global__ __launch_bounds__(256) void bin2(const int* __restrict__ esrc, const int* __restrict__ edst,
    int E, int nb_p, int* cu_p, unsigned* rec_p, int nb_t, int* cu_t, unsigned* rec_t, int nchunks){
  __shared__ int hist[256];
  __shared__ int excl[256];
  __shared__ int gbase[256];
  __shared__ unsigned recs[4096];
  __shared__ unsigned char binid[4096];
  if ((int)blockIdx.x < nchunks)
    bin_body(edst, esrc, E, 7, nb_p, cu_p, rec_p, blockIdx.x, hist, excl, gbase, recs, binid);
  else
    bin_body(esrc, edst, E, 9, nb_t, cu_t, rec_t, blockIdx.x - nchunks, hist, excl, gbase, recs, binid);
}

// ---------------- per-bucket CSR build body ----------------
template<int LOC, int LB>
__device__ inline void build_body(const unsigned* __restrict__ rec, const int* __restrict__ bbase,
    int nkeys, int E, int* __restrict__ off, float* __restrict__ inv, int* __restrict__ csr,
    int b, int nb, int* hist, int* excl, int* cur, int* wsum){
  int tid = threadIdx.x;
  int s = bbase[b], e = bbase[b + 1];
  for (int k = tid; k < LOC; k += 256){ hist[k] = 0; cur[k] = 0; }
  __syncthreads();
  for (int i = s + tid; i < e; i += 256) atomicAdd(&hist[rec[i] & (LOC - 1)], 1);
  __syncthreads();
  int lane = tid & 63, wid = tid >> 6;
  constexpr int BPT = (LOC + 255) / 256;
  int h[BPT]; int ssum = 0;
  #pragma unroll
  for (int q = 0; q < BPT; q++){
    int k = tid * BPT + q;
    h[q] = (k < LOC) ? hist[k] : 0;
    ssum += h[q];
  }
  int sc = ssum;
  #pragma unroll
  for (int o = 1; o < 64; o <<= 1){ int t = __shfl_up(sc, (unsigned)o, 64); if (lane >= o) sc += t; }
  if (lane == 63) wsum[wid] = sc;
  __syncthreads();
  int base = 0;
  for (int w = 0; w < wid; w++) base += wsum[w];
  int ex = base + sc - ssum;
  #pragma unroll
  for (int q = 0; q < BPT; q++){
    int k = tid * BPT + q;
    if (k < LOC) excl[k] = ex;
    ex += h[q];
  }
  __syncthreads();
  int keybase = b << LB;
  for (int k = tid; k < LOC; k += 256){
    int gk = keybase + k;
    if (gk < nkeys){
      off[gk] = s + excl[k];
      int c = hist[k];
      inv[gk] = 1.0f / (float)(c > 1 ? c : 1);
    }
  }
  if (b == nb - 1 && tid == 0) off[nkeys] = E;
  for (int i = s + tid; i < e; i += 256){
    unsigned r = rec[i];
    int k = (int)(r & (LOC - 1));
    int rk = atomicAdd(&cur[k], 1);
    csr[s + excl[k] + rk] = (int)(r >> LB);
  }
}

// merged build_csr: P buckets (LOC=128) then T buckets (LOC=512)
__global__ __launch_bounds__(256) void build2(
    const unsigned* rec_p, const int* bb_p, int NPk, int* off_p, float* inv_p, int* csr_p, int nb_p,
    const unsigned* rec_t, const int* bb_t, int NTk, int* off_t, float* inv_t, int* csr_t, int nb_t, int E){
  __shared__ int hist[512];
  __shared__ int excl[512];
  __shared__ int cur[512];
  __shared__ int wsum[8];
  if ((int)blockIdx.x < nb_p)
    build_body<128,7>(rec_p, bb_p, NPk, E, off_p, inv_p, csr_p, blockIdx.x, nb_p, hist, excl, cur, wsum);
  else
    build_body<512,9>(rec_t, bb_t, NTk, E, off_t, inv_t, csr_t, blockIdx.x - nb_p, nb_t, hist, excl, cur, wsum);
}

// ---------------- merged input projections (fp32 A -> f16 OUT), pipelined, single-f16 W ----------------
struct ProjJob {
  const float* A;
  const _Float16* WT;
  const float* bias;
  _Float16* OUT;
  int M;
  int ntiles;
  int nblk;
};
template<int KA>
__device__ inline void proj_body(ProjJob j, int bid, char* lds){
  constexpr int KST = KA / 32;
  constexpr int RB_A = KA * 4;
  constexpr int CHA = RB_A / 16;
  constexpr int NIA = 64 * CHA / 512;
  constexpr int ABYTES = 64 * RB_A;

  const int t    = threadIdx.x;
  const int wid  = t >> 6;
  const int lane = t & 63;
  const int l15  = lane & 15;
  const int lkg  = lane >> 4;
  const int colg = wid * 16 + l15;
  const int M = j.M, ntiles = j.ntiles, nblk = j.nblk;

  f16x8 wl[KST];
  {
    const _Float16* bh = j.WT + (size_t)colg * KA + lkg * 8;
    #pragma unroll
    for (int ks = 0; ks < KST; ks++) wl[ks] = *(const f16x8*)(bh + ks * 32);
  }
  const float bb = j.bias[colg];

  auto stage = [&](int tile, char* dstA){
    int row0 = tile * 64;
    #pragma unroll
    for (int q = 0; q < NIA; q++){
      int lc  = q * 512 + t;
      int row = lc / CHA;
      int ch  = lc - row * CHA;
      int grow = row0 + row; if (grow > M - 1) grow = M - 1;
      int gch = ch ^ (row & 7);
      gload_lds16((const char*)j.A + (size_t)grow * RB_A + gch * 16, dstA + lc * 16);
    }
  };

  int p = 0;
  if (bid < ntiles) stage(bid, lds);

  for (int t0 = bid; t0 < ntiles; t0 += nblk){
    const int row0 = t0 * 64;
    const int tn = t0 + nblk;
    const bool hasnext = tn < ntiles;
    if (hasnext) stage(tn, lds + (p ^ 1) * ABYTES);

    if (hasnext){
      if constexpr (NIA == 4) asm volatile("s_waitcnt vmcnt(4)" ::: "memory");
      else                    asm volatile("s_waitcnt vmcnt(2)" ::: "memory");
    } else {
      asm volatile("s_waitcnt vmcnt(0)" ::: "memory");
    }
    __builtin_amdgcn_s_barrier();
    asm volatile("" ::: "memory");

    const char* bufA = lds + p * ABYTES;

    f32x4 acc[4];
    #pragma unroll
    for (int tt = 0; tt < 4; tt++){
      acc[tt] = (f32x4){0.f, 0.f, 0.f, 0.f};
      const int rl = tt * 16 + l15;
      const int sw = rl & 7;
      const char* ap = bufA + rl * RB_A;
      #pragma unroll
      for (int ks = 0; ks < KST; ks++){
        int c0 = lkg * 2 + ks * 8;
        f32x4 a0 = *(const f32x4*)(ap + ((c0    ) ^ sw) * 16);
        f32x4 a1 = *(const f32x4*)(ap + ((c0 + 1) ^ sw) * 16);
        f16x8 af;
        #pragma unroll
        for (int e = 0; e < 8; e++) af[e] = (_Float16)(e < 4 ? a0[e] : a1[e - 4]);
        acc[tt] = mfma16h(af, wl[ks], acc[tt]);
      }
      acc[tt].x += bb; acc[tt].y += bb; acc[tt].z += bb; acc[tt].w += bb;
    }

    #pragma unroll
    for (int tt = 0; tt < 4; tt++){
      #pragma unroll
      for (int r = 0; r < 4; r++){
        int row = row0 + tt * 16 + lkg * 4 + r;
        if (row < M) j.OUT[(size_t)row * H + colg] = (_Float16)acc[tt][r];
      }
    }
    asm volatile("s_waitcnt lgkmcnt(0)" ::: "memory");
    __builtin_amdgcn_s_barrier();
    asm volatile("" ::: "memory");
    p ^= 1;
  }
}
__global__ __launch_bounds__(512) void proj2(ProjJob jt, ProjJob jp){
  __shared__ __align__(16) char lds[2 * 64 * 512];
  if ((int)blockIdx.x < jt.nblk) proj_body<128>(jt, blockIdx.x, lds);
  else                           proj_body<64>(jp, (int)blockIdx.x - jt.nblk, lds);
}

// ---------------- merged dual SAGE GEMM: two jobs (P and T), single-f16 W ----------------
struct SageJob {
  const _Float16* A;
  const _Float16* Bs;
  const _Float16* WlT;
  const _Float16* WrT;
  const float* bias;
  _Float16* OUT;
  int M;
  int ntiles;
  int nblk;
};
template<bool RELU>
__global__ __launch_bounds__(512, 8) void sage_mfma2(SageJob j0, SageJob j1){
  constexpr int KST = 4;
  constexpr int CHA = 16;
  constexpr int NIA = 2, NIB = 2;
  constexpr int ABYTES = 64 * 256;
  constexpr int BUFB = 2 * ABYTES;

  __shared__ __align__(16) char lds[2 * BUFB];
  __shared__ float red[8][64];

  const bool second = (int)blockIdx.x >= j0.nblk;
  const SageJob j = second ? j1 : j0;
  const int bid = (int)blockIdx.x - (second ? j0.nblk : 0);
  const int M = j.M, ntiles = j.ntiles, nblk = j.nblk;

  const int t    = threadIdx.x;
  const int wid  = t >> 6;
  const int lane = t & 63;
  const int l15  = lane & 15;
  const int lkg  = lane >> 4;
  const int colg = wid * 16 + l15;

  f16x8 wl[KST], wr[KST];
  {
    const _Float16* bh  = j.WlT + (size_t)colg * 128 + lkg * 8;
    const _Float16* bh2 = j.WrT + (size_t)colg * 128 + lkg * 8;
    #pragma unroll
    for (int ks = 0; ks < KST; ks++){
      wl[ks] = *(const f16x8*)(bh + ks * 32);
      wr[ks] = *(const f16x8*)(bh2 + ks * 32);
    }
  }
  const float bb = j.bias[colg];

  auto stage = [&](int tile, char* dstA, char* dstB){
    int row0 = tile * 64;
    #pragma unroll
    for (int q = 0; q < NIA; q++){
      int lc  = q * 512 + t;
      int row = lc / CHA;
      int ch  = lc - row * CHA;
      int grow = row0 + row; if (grow > M - 1) grow = M - 1;
      int gch = ch ^ (row & 7);
      gload_lds16((const char*)j.A + (size_t)grow * 256 + gch * 16, dstA + lc * 16);
    }
    #pragma unroll
    for (int q = 0; q < NIB; q++){
      int lc  = q * 512 + t;
      int row = lc >> 4;
      int ch  = lc & 15;
      int grow = row0 + row; if (grow > M - 1) grow = M - 1;
      int gch = ch ^ (row & 7);
      gload_lds16((const char*)j.Bs + (size_t)grow * 256 + gch * 16, dstB + lc * 16);
    }
  };

  int p = 0;
  if (bid < ntiles) stage(bid, lds, lds + ABYTES);

  for (int t0 = bid; t0 < ntiles; t0 += nblk){
    const int row0 = t0 * 64;
    const int tn = t0 + nblk;
    const bool hasnext = tn < ntiles;
    if (hasnext) stage(tn, lds + (p ^ 1) * BUFB, lds + (p ^ 1) * BUFB + ABYTES);

    if (hasnext) asm volatile("s_waitcnt vmcnt(4)" ::: "memory");
    else         asm volatile("s_waitcnt vmcnt(0)" ::: "memory");
    __builtin_amdgcn_s_barrier();
    asm volatile("" ::: "memory");

    const char* bufA = lds + p * BUFB;
    const char* bufB = bufA + ABYTES;

    f32x4 acc[4];
    #pragma unroll
    for (int tt = 0; tt < 4; tt++){
      acc[tt] = (f32x4){0.f, 0.f, 0.f, 0.f};
      const int rl = tt * 16 + l15;
      const int sw = rl & 7;
      const char* ap = bufA + rl * 256;
      #pragma unroll
      for (int ks = 0; ks < KST; ks++){
        f16x8 af = *(const f16x8*)(ap + ((ks * 4 + lkg) ^ sw) * 16);
        acc[tt] = mfma16h(af, wl[ks], acc[tt]);
      }
      const char* bp = bufB + rl * 256;
      #pragma unroll
      for (int ks = 0; ks < KST; ks++){
        f16x8 bf = *(const f16x8*)(bp + ((ks * 4 + lkg) ^ sw) * 16);
        acc[tt] = mfma16h(bf, wr[ks], acc[tt]);
      }
      acc[tt].x += bb; acc[tt].y += bb; acc[tt].z += bb; acc[tt].w += bb;
    }

    // l2norm
    #pragma unroll
    for (int tt = 0; tt < 4; tt++){
      #pragma unroll
      for (int r = 0; r < 4; r++){
        float v = acc[tt][r] * acc[tt][r];
        v += __shfl_xor(v, 1, 64);
        v += __shfl_xor(v, 2, 64);
        v += __shfl_xor(v, 4, 64);
        v += __shfl_xor(v, 8, 64);
        if (l15 == 0) red[wid][tt * 16 + lkg * 4 + r] = v;
      }
    }
    asm volatile("s_waitcnt lgkmcnt(0)" ::: "memory");
    __builtin_amdgcn_s_barrier();
    asm volatile("" ::: "memory");
    #pragma unroll
    for (int tt = 0; tt < 4; tt++){
      #pragma unroll
      for (int r = 0; r < 4; r++){
        int idx = tt * 16 + lkg * 4 + r;
        float s = 0.f;
        #pragma unroll
        for (int w2 = 0; w2 < 8; w2++) s += red[w2][idx];
        float scale = 1.f / fmaxf(sqrtf(s), 1e-12f);
        float v = acc[tt][r] * scale;
        if (RELU) v = fmaxf(v, 0.f);
        acc[tt][r] = v;
      }
    }
    #pragma unroll
    for (int tt = 0; tt < 4; tt++){
      #pragma unroll
      for (int r = 0; r < 4; r++){
        int row = row0 + tt * 16 + lkg * 4 + r;
        if (row < M) j.OUT[(size_t)row * H + colg] = (_Float16)acc[tt][r];
      }
    }
    p ^= 1;
  }
}

// ---------------- merged segment-mean: two gather jobs in one launch ----------------
struct AggJob {
  const _Float16* feat;
  const int* csr;
  const int* off;
  const float* inv;
  _Float16* out;
  int n;
  int nblk;   // blocks assigned to this job (16 rows/block)
};
__global__ __launch_bounds__(256) void agg2_kernel(AggJob j0, AggJob j1){
  const bool second = (int)blockIdx.x >= j0.nblk;
  const AggJob j = second ? j1 : j0;
  const int bid = (int)blockIdx.x - (second ? j0.nblk : 0);
  int g = bid * 16 + (threadIdx.x >> 4);
  int l = threadIdx.x & 15;
  if (g >= j.n) return;
  int s = j.off[g], e = j.off[g + 1];
  float c0[8], c1[8], c2[8], c3[8];
  #pragma unroll
  for (int q = 0; q < 8; q++){ c0[q] = 0.f; c1[q] = 0.f; c2[q] = 0.f; c3[q] = 0.f; }
  const _Float16* F = j.feat;
  int i = s;
  for (; i + 3 < e; i += 4){
    f16x8 v0 = *(const f16x8*)(F + (size_t)j.csr[i]     * H + l * 8);
    f16x8 v1 = *(const f16x8*)(F + (size_t)j.csr[i + 1] * H + l * 8);
    f16x8 v2 = *(const f16x8*)(F + (size_t)j.csr[i + 2] * H + l * 8);
    f16x8 v3 = *(const f16x8*)(F + (size_t)j.csr[i + 3] * H + l * 8);
    #pragma unroll
    for (int q = 0; q < 8; q++){
      c0[q] += (float)v0[q]; c1[q] += (float)v1[q];
      c2[q] += (float)v2[q]; c3[q] += (float)v3[q];
    }
  }
  for (; i < e; i++){
    f16x8 v0 = *(const f16x8*)(F + (size_t)j.csr[i] * H + l * 8);
    #pragma unroll
    for (int q = 0; q < 8; q++) c0[q] += (float)v0[q];
  }
  float iv = j.inv[g];
  f16x8 ov;
  #pragma unroll
  for (int q = 0; q < 8; q++){
    float r = (c0[q] + c1[q]) + (c2[q] + c3[q]);
    ov[q] = (_Float16)(r * iv);
  }
  *(f16x8*)(j.out + (size_t)g * H + l * 8) = ov;
}

// ---------------- link predictor: 16-lane group per pair, 16B loads ----------------
__global__ __launch_bounds__(256) void dot_kernel(const _Float16* __restrict__ zt, const _Float16* __restrict__ zp,
                           const int* __restrict__ ls, const int* __restrict__ ld,
                           float* __restrict__ out, int n){
  int w = (blockIdx.x * 256 + threadIdx.x) >> 4;
  int l = threadIdx.x & 15;
  if (w >= n) return;
  f16x8 x = *(const f16x8*)&zt[(size_t)ls[w] * H + l * 8];
  f16x8 y = *(const f16x8*)&zp[(size_t)ld[w] * H + l * 8];
  float v = 0.f;
  #pragma unroll
  for (int q = 0; q < 8; q++) v += (float)x[q] * (float)y[q];
  v += __shfl_xor(v, 1, 64);
  v += __shfl_xor(v, 2, 64);
  v += __shfl_xor(v, 4, 64);
  v += __shfl_xor(v, 8, 64);
  if (l == 0) out[w] = v;
}

extern "C" void kernel_launch(void* const* d_in, const int* in_sizes, int n_in,
                              void* d_out, int out_size, void* d_ws, size_t ws_size,
                              hipStream_t stream){
  const float* x_t  = (const float*)d_in[0];
  const float* x_p  = (const float*)d_in[1];
  const int*   esrc = (const int*)d_in[2];
  const int*   edst = (const int*)d_in[3];
  const int*   lsrc = (const int*)d_in[4];
  const int*   ldst = (const int*)d_in[5];
  const float* Wn_t = (const float*)d_in[6];
  const float* bn_t = (const float*)d_in[7];
  const float* Wn_p = (const float*)d_in[8];
  const float* bn_p = (const float*)d_in[9];
  const float* W1_l_p=(const float*)d_in[10]; const float* b1_p=(const float*)d_in[11]; const float* W1_r_p=(const float*)d_in[12];
  const float* W1_l_t=(const float*)d_in[13]; const float* b1_t=(const float*)d_in[14]; const float* W1_r_t=(const float*)d_in[15];
  const float* W2_l_p=(const float*)d_in[16]; const float* b2_p=(const float*)d_in[17]; const float* W2_r_p=(const float*)d_in[18];
  const float* W2_l_t=(const float*)d_in[19]; const float* b2_t=(const float*)d_in[20]; const float* W2_r_t=(const float*)d_in[21];
  float* out = (float*)d_out;

  const int FT = 128, FP = 64;
  int NT = in_sizes[0] / FT;
  int NP = in_sizes[1] / FP;
  int E  = in_sizes[2];
  int EL = in_sizes[4];

  const int SH_P = 7, SH_T = 9;
  int nb_p = (NP + (1 << SH_P) - 1) >> SH_P;
  int nb_t = (NT + (1 << SH_T) - 1) >> SH_T;

  char* base = (char*)d_ws;
  size_t o = 0;
  auto alloc = [&](size_t bytes) -> char* { char* p = base + o; o = align_up(o + bytes, 256); return p; };
  int*   cb_p  = (int*)alloc(256 * 4);
  int*   cb_t  = (int*)alloc(256 * 4);
  size_t zero_bytes = o;
  int*   bb_p  = (int*)alloc(260 * 4);
  int*   bb_t  = (int*)alloc(260 * 4);
  int*   cu_p  = (int*)alloc(256 * 4);
  int*   cu_t  = (int*)alloc(256 * 4);
  int*   off_p = (int*)alloc((size_t)(NP + 1) * 4);
  int*   off_t = (int*)alloc((size_t)(NT + 1) * 4);
  float* inv_p = (float*)alloc((size_t)NP * 4);
  float* inv_t = (float*)alloc((size_t)NT * 4);
  unsigned* rec_p = (unsigned*)alloc((size_t)E * 4);
  unsigned* rec_t = (unsigned*)alloc((size_t)E * 4);
  int*   csr_p = (int*)alloc((size_t)E * 4);
  int*   csr_t = (int*)alloc((size_t)E * 4);
  _Float16* h_t = (_Float16*)alloc((size_t)NT * H * 2);
  _Float16* h_p = (_Float16*)alloc((size_t)NP * H * 2);
  _Float16* a_t = (_Float16*)alloc((size_t)NT * H * 2);
  _Float16* a_p = (_Float16*)alloc((size_t)NP * H * 2);

  PackArgs pa;
  const float* wsrc[10] = {Wn_t, Wn_p, W1_l_p, W1_r_p, W1_l_t, W1_r_t, W2_l_p, W2_r_p, W2_l_t, W2_r_t};
  int Ks[10] = {128, 64, 128, 128, 128, 128, 128, 128, 128, 128};
  _Float16* wpk[10];
  int st = 0;
  for (int m = 0; m < 10; m++){
    wpk[m] = (_Float16*)alloc((size_t)128 * Ks[m] * 2);
    pa.src[m] = wsrc[m]; pa.dst[m] = wpk[m]; pa.K[m] = Ks[m]; pa.start[m] = st;
    st += Ks[m] * 128;
  }
  pa.start[10] = st;
  (void)ws_size; (void)n_in; (void)out_size;

  hipMemsetAsync(base, 0, zero_bytes, stream);

  // merged pack_w + bucket histograms
  int nblk_pack = (st + 255) / 256;
  const int histgrid = 512;
  pack_hist<<<nblk_pack + histgrid, 256, 0, stream>>>(pa, nblk_pack, esrc, edst, E, cb_p, cb_t, histgrid);
  scan_buckets<<<1, 64, 0, stream>>>(cb_p, cb_t, nb_p, nb_t, bb_p, bb_t, cu_p, cu_t);
  int nchunks = (E + 4095) / 4096;
  bin2<<<2 * nchunks, 256, 0, stream>>>(esrc, edst, E, nb_p, cu_p, rec_p, nb_t, cu_t, rec_t, nchunks);
  build2<<<nb_p + nb_t, 256, 0, stream>>>(rec_p, bb_p, NP, off_p, inv_p, csr_p, nb_p,
                                          rec_t, bb_t, NT, off_t, inv_t, csr_t, nb_t, E);

  // merged input projections
  int tiles_t = (NT + 63) / 64;
  int tiles_p = (NP + 63) / 64;
  int pblk_t = tiles_t < 448 ? tiles_t : 448;
  int pblk_p = tiles_p < 64 ? tiles_p : 64;
  ProjJob pjt{x_t, wpk[0], bn_t, h_t, NT, tiles_t, pblk_t};
  ProjJob pjp{x_p, wpk[1], bn_p, h_p, NP, tiles_p, pblk_p};
  proj2<<<pblk_t + pblk_p, 512, 0, stream>>>(pjt, pjp);

  // merged agg jobs: 16 rows per block
  int ablk_p = (NP + 15) / 16;
  int ablk_t = (NT + 15) / 16;
  AggJob aj_p1{h_t, csr_p, off_p, inv_p, a_p, NP, ablk_p};
  AggJob aj_t1{h_p, csr_t, off_t, inv_t, a_t, NT, ablk_t};
  AggJob aj_p2{a_t, csr_p, off_p, inv_p, h_p, NP, ablk_p};
  AggJob aj_t2{a_p, csr_t, off_t, inv_t, h_t, NT, ablk_t};

  // merged sage jobs
  int nblk_p = tiles_p < 96 ? tiles_p : 96;
  int nblk_t = tiles_t < 416 ? tiles_t : 416;
  SageJob sj1p{a_p, h_p, wpk[2], wpk[3], b1_p, a_p, NP, tiles_p, nblk_p};
  SageJob sj1t{a_t, h_t, wpk[4], wpk[5], b1_t, a_t, NT, tiles_t, nblk_t};
  SageJob sj2p{h_p, a_p, wpk[6], wpk[7], b2_p, h_p, NP, tiles_p, nblk_p};
  SageJob sj2t{h_t, a_t, wpk[8], wpk[9], b2_t, h_t, NT, tiles_t, nblk_t};

  // layer 1
  agg2_kernel<<<ablk_p + ablk_t, 256, 0, stream>>>(aj_p1, aj_t1);
  sage_mfma2<true><<<nblk_p + nblk_t, 512, 0, stream>>>(sj1p, sj1t);

  // layer 2
  agg2_kernel<<<ablk_p + ablk_t, 256, 0, stream>>>(aj_p2, aj_t2);
  sage_mfma2<false><<<nblk_p + nblk_t, 512, 0, stream>>>(sj2p, sj2t);

  // link prediction
  dot_kernel<<<(EL + 15) / 16, 256, 0, stream>>>(h_t, h_p, lsrc, ldst, out, EL);
}